// Round 13
// baseline (938.603 us; speedup 1.0000x reference)
//
#include <hip/hip_runtime.h>
#include <hip/hip_bf16.h>

// GAT, 2 layers, N=8192 nodes, sparse adjacency (~270K edges incl. self-loops).
// Masked softmax with -1e9 fill == sparse neighbor softmax (exp underflows to 0).
// Round 12: mega-kernel barrier FIX. Round 11's spin used agent-scope ACQUIRE
// loads -> buffer_inv (L1+L2 invalidate) EVERY spin iteration -> 1024 blocks
// storming the coherence fabric = 1118us with all pipes idle. Standard pattern:
// RELAXED spin + s_sleep backoff; synchronization via fences only (one wbl2
// release before arrive, one inv acquire per wave after exit).
// Workspace (~26 MB + 64B ctr): same map as round 8, ctr at +26MB.

#define NN 8192
#define MAXD 128  // weight-phase slots; P(in-degree>128) ~ 1e-18 (Poisson 32)
#define GRID 1024

typedef __bf16 bf16x8 __attribute__((ext_vector_type(8)));
typedef float f32x4 __attribute__((ext_vector_type(4)));
typedef unsigned short u16x8 __attribute__((ext_vector_type(8)));

__device__ __forceinline__ unsigned short f2bf(float f) {
  unsigned u = __float_as_uint(f);
  unsigned r = (u + 0x7fffu + ((u >> 16) & 1u)) >> 16;  // round-nearest-even
  return (unsigned short)r;
}
__device__ __forceinline__ float bf2f(unsigned short u) {
  return __uint_as_float(((unsigned)u) << 16);
}
__device__ __forceinline__ float lrelu02(float e) { return e > 0.f ? e : 0.2f * e; }

// Software grid barrier, cooperative-groups pattern. Deadlock-free iff all
// blocks co-resident (1024 blocks = 4/CU at <=128 VGPR, 16KB LDS; verified
// round 11: occupancy 49%, no hang). Synchronization via fence-to-fence:
// release __threadfence (buffer_wbl2) BEFORE relaxed arrive; RELAXED spin
// (plain coherent loads, NO per-iteration invalidate — round 11's bug was
// ACQUIRE spin loads emitting buffer_inv each iteration); acquire
// __threadfence (one buffer_inv per wave) after exit.
__device__ __forceinline__ void grid_barrier(unsigned* __restrict__ ctr, int idx) {
  __syncthreads();
  if (threadIdx.x == 0) {
    __threadfence();  // release: write back this XCD's dirty L2 lines
    __hip_atomic_fetch_add(ctr + idx, 1u, __ATOMIC_RELAXED, __HIP_MEMORY_SCOPE_AGENT);
    while (__hip_atomic_load(ctr + idx, __ATOMIC_RELAXED, __HIP_MEMORY_SCOPE_AGENT) <
           gridDim.x)
      __builtin_amdgcn_s_sleep(8);
  }
  __syncthreads();
  __threadfence();  // acquire: one L1/L2 invalidate per wave, then proceed
}

__global__ __launch_bounds__(256, 4) void gat_mega_kernel(
    const float* __restrict__ X, const int* __restrict__ ei, const int E,
    const float* __restrict__ W1, const float* __restrict__ A1S,
    const float* __restrict__ A1D, const float* __restrict__ W2,
    const float* __restrict__ A2S, const float* __restrict__ A2D,
    unsigned short* __restrict__ h1b, unsigned short* __restrict__ out1b,
    unsigned* __restrict__ bitmap, float* __restrict__ f1s, float* __restrict__ f1d,
    float* __restrict__ h2, float* __restrict__ f2s, float* __restrict__ f2d,
    int* __restrict__ degarr, unsigned short* __restrict__ w1t,
    unsigned short* __restrict__ w2t, unsigned* __restrict__ ctr,
    float* __restrict__ out) {
  __shared__ __align__(16) unsigned char smem[16384];  // gemm1: 16KB; attn: 4KB
  const int tid = threadIdx.x;
  const int wv = tid >> 6, lane = tid & 63;
  const int lr = lane & 15, lg = lane >> 4;
  const int G = gridDim.x;
  const int gtid = blockIdx.x * 256 + tid;
  const int T = G * 256;
  const int gwave = blockIdx.x * 4 + wv;
  const int NW = G * 4;

  // ===== phase 0: zero bitmap + f1s/f1d, transpose W1/W2 to bf16 =====
  {
    uint4* b4 = (uint4*)bitmap;
    const uint4 z = {0u, 0u, 0u, 0u};
    for (int i = gtid; i < (NN * 256) / 4; i += T) b4[i] = z;
    for (int i = gtid; i < 256 * 512; i += T) {
      const int n = i >> 9, k = i & 511;
      w1t[i] = f2bf(W1[(size_t)k * 256 + n]);  // W1t[n][k]
    }
    for (int i = gtid; i < 16 * 256; i += T) {
      const int n = i >> 8, k = i & 255;
      w2t[i] = f2bf(W2[(size_t)k * 16 + n]);   // W2t[n][k]
    }
    float4* fz4 = (float4*)f1s;  // f1s ++ f1d contiguous: 4096 float4
    const float4 fz = {0.f, 0.f, 0.f, 0.f};
    for (int i = gtid; i < 4096; i += T) fz4[i] = fz;
  }
  grid_barrier(ctr, 0);

  // ===== phase 1: scatter edges into bitmap (device-scope atomicOr) =====
  for (int i = gtid; i < E; i += T) {
    const int s = ei[i];
    const int d = ei[E + i];
    atomicOr(bitmap + (size_t)s * 256 + (d >> 5), 1u << (d & 31));
  }
  grid_barrier(ctr, 1);

  // ===== phase 2: build CSR in place (one wave per row) =====
  for (int row = gwave; row < NN; row += NW) {
    unsigned* brow = bitmap + (size_t)row * 256;
    const uint4 wq = *(const uint4*)(brow + lane * 4);
    const int cnt = __popc(wq.x) + __popc(wq.y) + __popc(wq.z) + __popc(wq.w);
    int inc = cnt;
#pragma unroll
    for (int d = 1; d < 64; d <<= 1) {
      const int t2 = __shfl_up(inc, d);
      if (lane >= d) inc += t2;
    }
    int off = inc - cnt;  // exclusive prefix
    const int total = __shfl(inc, 63);
    unsigned short* nbp = (unsigned short*)brow;
    const unsigned words[4] = {wq.x, wq.y, wq.z, wq.w};
    const int base_j = lane * 128;
#pragma unroll
    for (int q = 0; q < 4; ++q) {
      unsigned word = words[q];
      while (word) {
        const int b = __ffs(word) - 1;
        word &= word - 1;
        nbp[off++] = (unsigned short)(base_j + q * 32 + b);
      }
    }
    if (lane == 0) degarr[row] = total;
  }
  grid_barrier(ctr, 2);

  // ===== phase 3: gemm1 (MFMA, 64x64 tile, XOR-swizzled LDS) + fused f1 =====
  for (int tile = blockIdx.x; tile < 512; tile += G) {
    constexpr int K = 512;
    unsigned short* lds = (unsigned short*)smem;  // 512 A units + 512 B units
    const int bm = (tile >> 2) * 64, bn = (tile & 3) * 64;
    const int r8 = tid >> 3, c8 = tid & 7;
    f32x4 acc[4];
    const f32x4 fzv = {0.f, 0.f, 0.f, 0.f};
#pragma unroll
    for (int cb = 0; cb < 4; ++cb) acc[cb] = fzv;

    for (int k0 = 0; k0 < K; k0 += 64) {
      float4 xa[2][2];
#pragma unroll
      for (int p = 0; p < 2; ++p) {
        const float* s = X + (size_t)(bm + r8 + p * 32) * K + k0 + c8 * 8;
        xa[p][0] = *(const float4*)s;
        xa[p][1] = *(const float4*)(s + 4);
      }
      uint4 wb[2];
#pragma unroll
      for (int p = 0; p < 2; ++p)
        wb[p] = *(const uint4*)(w1t + (size_t)(bn + r8 + p * 32) * K + k0 + c8 * 8);
      __syncthreads();
#pragma unroll
      for (int p = 0; p < 2; ++p) {
        const int row = r8 + p * 32;
        const int u = ((row >> 4) << 7) + ((c8 >> 2) << 6) + ((c8 & 3) << 4) + ((row & 15) ^ c8);
        u16x8 v;
        v[0] = f2bf(xa[p][0].x); v[1] = f2bf(xa[p][0].y);
        v[2] = f2bf(xa[p][0].z); v[3] = f2bf(xa[p][0].w);
        v[4] = f2bf(xa[p][1].x); v[5] = f2bf(xa[p][1].y);
        v[6] = f2bf(xa[p][1].z); v[7] = f2bf(xa[p][1].w);
        *(u16x8*)(lds + u * 8) = v;
      }
#pragma unroll
      for (int p = 0; p < 2; ++p) {
        const int row = r8 + p * 32;
        const int u = 512 + ((row >> 4) << 7) + ((c8 >> 2) << 6) + ((c8 & 3) << 4) + ((row & 15) ^ c8);
        *(uint4*)(lds + u * 8) = wb[p];
      }
      __syncthreads();
#pragma unroll
      for (int ks = 0; ks < 2; ++ks) {
        const int xr = lr ^ (ks * 4 + lg);
        const bf16x8 a = *(const bf16x8*)(lds + ((wv << 7) + (ks << 6) + (lg << 4) + xr) * 8);
        const bf16x8 b0 = *(const bf16x8*)(lds + (512 + (0 << 7) + (ks << 6) + (lg << 4) + xr) * 8);
        const bf16x8 b1 = *(const bf16x8*)(lds + (512 + (1 << 7) + (ks << 6) + (lg << 4) + xr) * 8);
        const bf16x8 b2 = *(const bf16x8*)(lds + (512 + (2 << 7) + (ks << 6) + (lg << 4) + xr) * 8);
        const bf16x8 b3 = *(const bf16x8*)(lds + (512 + (3 << 7) + (ks << 6) + (lg << 4) + xr) * 8);
        acc[0] = __builtin_amdgcn_mfma_f32_16x16x32_bf16(a, b0, acc[0], 0, 0, 0);
        acc[1] = __builtin_amdgcn_mfma_f32_16x16x32_bf16(a, b1, acc[1], 0, 0, 0);
        acc[2] = __builtin_amdgcn_mfma_f32_16x16x32_bf16(a, b2, acc[2], 0, 0, 0);
        acc[3] = __builtin_amdgcn_mfma_f32_16x16x32_bf16(a, b3, acc[3], 0, 0, 0);
      }
    }
    // C-write; C/D layout: row=(l>>4)*4+q, col=l&15 (m89-verified)
#pragma unroll
    for (int cb = 0; cb < 4; ++cb)
#pragma unroll
      for (int q = 0; q < 4; ++q) {
        const int row = bm + wv * 16 + lg * 4 + q;
        h1b[(size_t)row * 256 + bn + cb * 16 + lr] = f2bf(acc[cb][q]);
      }
    // fused f1: partial dots over this tile's 64 cols, device-scope atomicAdd
    float a1sv[4], a1dv[4];
#pragma unroll
    for (int cb = 0; cb < 4; ++cb) {
      a1sv[cb] = A1S[bn + cb * 16 + lr];
      a1dv[cb] = A1D[bn + cb * 16 + lr];
    }
#pragma unroll
    for (int q = 0; q < 4; ++q) {
      float ps = 0.f, pd = 0.f;
#pragma unroll
      for (int cb = 0; cb < 4; ++cb) {
        ps = fmaf(acc[cb][q], a1sv[cb], ps);
        pd = fmaf(acc[cb][q], a1dv[cb], pd);
      }
#pragma unroll
      for (int off = 8; off; off >>= 1) {
        ps += __shfl_xor(ps, off, 16);
        pd += __shfl_xor(pd, off, 16);
      }
      if (lr == 0) {
        const int row = bm + wv * 16 + lg * 4 + q;
        atomicAdd(f1s + row, ps);
        atomicAdd(f1d + row, pd);
      }
    }
  }
  grid_barrier(ctr, 3);

  // ===== phase 4: layer-1 attention =====
  {
    float* wsh = (float*)smem;                 // [4][MAXD]
    int* jsh = (int*)(smem + 4 * MAXD * 4);    // [4][MAXD]
    for (int row = gwave; row < NN; row += NW) {
      const unsigned short* nbp = (const unsigned short*)(bitmap + (size_t)row * 256);
      const int deg = degarr[row];
      const float fsr = f1s[row];
      const int j0 = (lane < deg) ? (int)nbp[lane] : 0;
      const int j1 = (lane + 64 < deg) ? (int)nbp[lane + 64] : 0;
      const float e0 = (lane < deg) ? lrelu02(fsr + f1d[j0]) : -1e30f;
      const float e1 = (lane + 64 < deg) ? lrelu02(fsr + f1d[j1]) : -1e30f;
      float m = fmaxf(e0, e1);
#pragma unroll
      for (int off = 32; off; off >>= 1) m = fmaxf(m, __shfl_xor(m, off));
      const float w0 = (lane < deg) ? expf(e0 - m) : 0.f;
      const float w1 = (lane + 64 < deg) ? expf(e1 - m) : 0.f;
      float s = w0 + w1;
#pragma unroll
      for (int off = 32; off; off >>= 1) s += __shfl_xor(s, off);
      wsh[wv * MAXD + lane] = w0;
      jsh[wv * MAXD + lane] = j0;
      wsh[wv * MAXD + lane + 64] = w1;
      jsh[wv * MAXD + lane + 64] = j1;
      // gather: wave halves take alternating neighbors; 16B per lane
      const int half = lane >> 5, lh = lane & 31;
      float acc[8] = {0.f, 0.f, 0.f, 0.f, 0.f, 0.f, 0.f, 0.f};
      int t = 0;
      for (; t + 8 <= deg; t += 8) {
        const int ja = jsh[wv * MAXD + t + half], jb = jsh[wv * MAXD + t + 2 + half];
        const int jc = jsh[wv * MAXD + t + 4 + half], jd = jsh[wv * MAXD + t + 6 + half];
        const float Wa = wsh[wv * MAXD + t + half], Wb = wsh[wv * MAXD + t + 2 + half];
        const float Wc = wsh[wv * MAXD + t + 4 + half], Wd = wsh[wv * MAXD + t + 6 + half];
        const u16x8 va = *(const u16x8*)(h1b + (size_t)ja * 256 + lh * 8);
        const u16x8 vb = *(const u16x8*)(h1b + (size_t)jb * 256 + lh * 8);
        const u16x8 vc = *(const u16x8*)(h1b + (size_t)jc * 256 + lh * 8);
        const u16x8 vd = *(const u16x8*)(h1b + (size_t)jd * 256 + lh * 8);
#pragma unroll
        for (int e = 0; e < 8; ++e)
          acc[e] = fmaf(Wa, bf2f(va[e]),
                   fmaf(Wb, bf2f(vb[e]), fmaf(Wc, bf2f(vc[e]), fmaf(Wd, bf2f(vd[e]), acc[e]))));
      }
      for (; t < deg; t += 2) {
        const int idx = t + half;
        const int jt = (idx < deg) ? jsh[wv * MAXD + idx] : 0;
        const float Wt = (idx < deg) ? wsh[wv * MAXD + idx] : 0.f;
        const u16x8 v = *(const u16x8*)(h1b + (size_t)jt * 256 + lh * 8);
#pragma unroll
        for (int e = 0; e < 8; ++e) acc[e] = fmaf(Wt, bf2f(v[e]), acc[e]);
      }
#pragma unroll
      for (int e = 0; e < 8; ++e) acc[e] += __shfl_xor(acc[e], 32);
      const float inv = 1.f / s;
      u16x8 o;
#pragma unroll
      for (int e = 0; e < 8; ++e) {
        float v = acc[e] * inv;
        v = v > 0.f ? v : expf(v) - 1.f;  // elu
        o[e] = f2bf(v);
      }
      if (lane < 32) *(u16x8*)(out1b + (size_t)row * 256 + lh * 8) = o;
    }
  }
  grid_barrier(ctr, 4);

  // ===== phase 5: gemm2 (MFMA) + fused f2 (one wave per 16 rows) =====
  for (int job = gwave; job < NN / 16; job += NW) {
    const int row0 = job * 16;
    f32x4 acc = {0.f, 0.f, 0.f, 0.f};
#pragma unroll
    for (int k0 = 0; k0 < 256; k0 += 32) {
      const bf16x8 a = *(const bf16x8*)(out1b + (size_t)(row0 + lr) * 256 + k0 + lg * 8);
      const bf16x8 b = *(const bf16x8*)(w2t + (size_t)lr * 256 + k0 + lg * 8);
      acc = __builtin_amdgcn_mfma_f32_16x16x32_bf16(a, b, acc, 0, 0, 0);
    }
    const float as = A2S[lr], ad = A2D[lr];
#pragma unroll
    for (int q = 0; q < 4; ++q) {
      const int row = row0 + lg * 4 + q;  // C/D: row=(l>>4)*4+q, col=l&15
      const float v = acc[q];
      h2[(size_t)row * 16 + lr] = v;
      float ss = v * as, dd = v * ad;
#pragma unroll
      for (int off = 8; off; off >>= 1) {
        ss += __shfl_xor(ss, off, 16);
        dd += __shfl_xor(dd, off, 16);
      }
      if (lr == 0) {
        f2s[row] = ss;
        f2d[row] = dd;
      }
    }
  }
  grid_barrier(ctr, 5);

  // ===== phase 6: layer-2 attention + final log_softmax =====
  {
    float* wsh = (float*)smem;
    int* jsh = (int*)(smem + 4 * MAXD * 4);
    for (int row = gwave; row < NN; row += NW) {
      const unsigned short* nbp = (const unsigned short*)(bitmap + (size_t)row * 256);
      const int deg = degarr[row];
      const float fsr = f2s[row];
      const int j0 = (lane < deg) ? (int)nbp[lane] : 0;
      const int j1 = (lane + 64 < deg) ? (int)nbp[lane + 64] : 0;
      const float e0 = (lane < deg) ? lrelu02(fsr + f2d[j0]) : -1e30f;
      const float e1 = (lane + 64 < deg) ? lrelu02(fsr + f2d[j1]) : -1e30f;
      float m = fmaxf(e0, e1);
#pragma unroll
      for (int off = 32; off; off >>= 1) m = fmaxf(m, __shfl_xor(m, off));
      const float w0 = (lane < deg) ? expf(e0 - m) : 0.f;
      const float w1 = (lane + 64 < deg) ? expf(e1 - m) : 0.f;
      float s = w0 + w1;
#pragma unroll
      for (int off = 32; off; off >>= 1) s += __shfl_xor(s, off);
      wsh[wv * MAXD + lane] = w0;
      jsh[wv * MAXD + lane] = j0;
      wsh[wv * MAXD + lane + 64] = w1;
      jsh[wv * MAXD + lane + 64] = j1;
      const int c = lane & 15, g = lane >> 4;
      float acc = 0.f;
      int t = g;
      for (; t + 12 < deg; t += 16) {
        const float W0 = wsh[wv * MAXD + t], W1 = wsh[wv * MAXD + t + 4];
        const float W2 = wsh[wv * MAXD + t + 8], W3 = wsh[wv * MAXD + t + 12];
        const float v0 = h2[(size_t)jsh[wv * MAXD + t] * 16 + c];
        const float v1 = h2[(size_t)jsh[wv * MAXD + t + 4] * 16 + c];
        const float v2 = h2[(size_t)jsh[wv * MAXD + t + 8] * 16 + c];
        const float v3 = h2[(size_t)jsh[wv * MAXD + t + 12] * 16 + c];
        acc = fmaf(W0, v0, fmaf(W1, v1, fmaf(W2, v2, fmaf(W3, v3, acc))));
      }
      for (; t < deg; t += 4)
        acc = fmaf(wsh[wv * MAXD + t], h2[(size_t)jsh[wv * MAXD + t] * 16 + c], acc);
      acc += __shfl_xor(acc, 16);
      acc += __shfl_xor(acc, 32);
      const float v = acc / s;  // logits
      float mx = v;
#pragma unroll
      for (int off = 8; off; off >>= 1) mx = fmaxf(mx, __shfl_xor(mx, off, 16));
      float se = expf(v - mx);
#pragma unroll
      for (int off = 8; off; off >>= 1) se += __shfl_xor(se, off, 16);
      if (lane < 16) out[(size_t)row * 16 + lane] = v - mx - logf(se);
    }
  }
}

extern "C" void kernel_launch(void* const* d_in, const int* in_sizes, int n_in,
                              void* d_out, int out_size, void* d_ws, size_t ws_size,
                              hipStream_t stream) {
  const float* x = (const float*)d_in[0];
  const int* ei = (const int*)d_in[1];
  const float* W1 = (const float*)d_in[2];
  const float* a1s = (const float*)d_in[3];
  const float* a1d = (const float*)d_in[4];
  const float* W2 = (const float*)d_in[5];
  const float* a2s = (const float*)d_in[6];
  const float* a2d = (const float*)d_in[7];
  float* out = (float*)d_out;
  const int E = in_sizes[1] / 2;

  char* ws = (char*)d_ws;
  unsigned short* h1b = (unsigned short*)ws;                   // 4 MB
  unsigned short* out1b = (unsigned short*)(ws + (4u << 20));  // 4 MB
  unsigned* bitmap = (unsigned*)(ws + (16u << 20));            // 8 MB, reused as CSR
  float* f1s = (float*)(ws + (24u << 20));
  float* f1d = f1s + NN;
  float* h2 = f1d + NN;                                        // 512 KB
  float* f2s = h2 + (size_t)NN * 16;
  float* f2d = f2s + NN;
  int* deg = (int*)(f2d + NN);
  unsigned short* w1t = (unsigned short*)(deg + NN);           // 256 KB
  unsigned short* w2t = w1t + (size_t)256 * 512;               // 8 KB
  unsigned* ctr = (unsigned*)(ws + (26u << 20));               // 6 barrier counters

  hipMemsetAsync(ctr, 0, 64, stream);
  gat_mega_kernel<<<GRID, 256, 0, stream>>>(x, ei, E, W1, a1s, a1d, W2, a2s, a2d,
                                            h1b, out1b, bitmap, f1s, f1d, h2, f2s,
                                            f2d, deg, w1t, w2t, ctr, out);
}

// Round 14
// 71.048 us; speedup vs baseline: 13.2109x; 13.2109x over previous
//
#include <hip/hip_runtime.h>
#include <hip/hip_bf16.h>

// GAT, 2 layers, N=8192 nodes, sparse adjacency (~270K edges incl. self-loops).
// Masked softmax with -1e9 fill == sparse neighbor softmax (exp underflows to 0).
// Round 14: REVERT mega-kernel (rounds 11-13: software grid barriers cost
// ~150us each — per-block wbl2 + per-wave inv = thousands of full L2 tag-walks
// per barrier vs the driver's one per kernel boundary; pre-committed revert
// rule triggered). Back to round-10 pipeline + merge: scatter || gemm1+f1 in
// ONE kernel (independent work, block-range split; scatter's random atomics
// overlap gemm1's MFMA). 6 launches.
// Workspace layout (~26 MB): unchanged from round 8.

#define NN 8192
#define MAXD 128  // weight-phase slots; P(in-degree>128) ~ 1e-18 (Poisson 32)

typedef __bf16 bf16x8 __attribute__((ext_vector_type(8)));
typedef float f32x4 __attribute__((ext_vector_type(4)));
typedef unsigned short u16x8 __attribute__((ext_vector_type(8)));

__device__ __forceinline__ unsigned short f2bf(float f) {
  unsigned u = __float_as_uint(f);
  unsigned r = (u + 0x7fffu + ((u >> 16) & 1u)) >> 16;  // round-nearest-even
  return (unsigned short)r;
}
__device__ __forceinline__ float bf2f(unsigned short u) {
  return __uint_as_float(((unsigned)u) << 16);
}
__device__ __forceinline__ float lrelu02(float e) { return e > 0.f ? e : 0.2f * e; }

// ---------- prep: zero bitmap + f1s/f1d, W1^T bf16, W2^T bf16 ----------
__global__ __launch_bounds__(256) void prep_kernel(uint4* __restrict__ bitmap,
                                                   const float* __restrict__ W1,
                                                   unsigned short* __restrict__ W1t,
                                                   const float* __restrict__ W2,
                                                   unsigned short* __restrict__ W2t,
                                                   float4* __restrict__ f1sd) {
  const int bid = blockIdx.x, tid = threadIdx.x;
  if (bid < 2048) {
    bitmap[bid * 256 + tid] = uint4{0u, 0u, 0u, 0u};
  } else if (bid < 2560) {
    const int gid = (bid - 2048) * 256 + tid;  // 131072 total
    const int n = gid >> 9, k = gid & 511;
    W1t[gid] = f2bf(W1[(size_t)k * 256 + n]);  // W1t[n][k]
  } else if (bid == 2560) {
    for (int i = tid; i < 16 * 256; i += 256) {
      const int n = i >> 8, k = i & 255;
      W2t[i] = f2bf(W2[(size_t)k * 16 + n]);   // W2t[n][k]
    }
  } else {
    // zero f1s[8192] ++ f1d[8192] (contiguous): 4096 float4
    for (int i = tid; i < 4096; i += 256) f1sd[i] = float4{0.f, 0.f, 0.f, 0.f};
  }
}

// ---------- merged: scatter (blocks [0,SB)) || gemm1 MFMA + fused f1 (blocks [SB,SB+512)) ----------
// Independent inputs (bitmap-zero vs w1t, both from prep), disjoint outputs
// (bitmap vs h1b/f1s/f1d) -> safe to co-schedule. Scatter blocks dispatch
// first so the random atomicOr traffic overlaps gemm1's compute.
// gemm1: 64x64 tile, BK=64, 4 waves; XOR-swizzled LDS (round-10 verified:
// write-side conflict-free, read 2-way=free; A/B share map -> k-perm cancels).
__global__ __launch_bounds__(256) void gemm1_scatter_kernel(
    const float* __restrict__ X, const unsigned short* __restrict__ W1t,
    unsigned short* __restrict__ h1b, const float* __restrict__ A1S,
    const float* __restrict__ A1D, float* __restrict__ f1s, float* __restrict__ f1d,
    const int* __restrict__ ei, const int E, const int SB,
    unsigned* __restrict__ bitmap) {
  __shared__ __align__(16) unsigned short lds[1024 * 8];  // 16 KB (gemm path only)
  if (blockIdx.x < SB) {  // ---- scatter path (whole-block branch) ----
    const int t = blockIdx.x * 256 + threadIdx.x;
    if (t < E) {
      const int s = ei[t];
      const int d = ei[E + t];
      atomicOr(bitmap + (size_t)s * 256 + (d >> 5), 1u << (d & 31));
    }
    return;
  }
  // ---- gemm1 path ----
  constexpr int K = 512;
  const int tile = blockIdx.x - SB;  // 0..511
  const int t = threadIdx.x;
  const int w = t >> 6, l = t & 63;
  const int lr = l & 15, lg = l >> 4;
  const int bm = (tile >> 2) * 64, bn = (tile & 3) * 64;
  const int r8 = t >> 3, c8 = t & 7;  // staging coords: row r8(+32), 16B k-chunk c8

  f32x4 acc[4];
  const f32x4 fz = {0.f, 0.f, 0.f, 0.f};
#pragma unroll
  for (int cb = 0; cb < 4; ++cb) acc[cb] = fz;

  for (int k0 = 0; k0 < K; k0 += 64) {
    float4 xa[2][2];
#pragma unroll
    for (int p = 0; p < 2; ++p) {
      const float* s = X + (size_t)(bm + r8 + p * 32) * K + k0 + c8 * 8;
      xa[p][0] = *(const float4*)s;
      xa[p][1] = *(const float4*)(s + 4);
    }
    uint4 wb[2];
#pragma unroll
    for (int p = 0; p < 2; ++p)
      wb[p] = *(const uint4*)(W1t + (size_t)(bn + r8 + p * 32) * K + k0 + c8 * 8);
    __syncthreads();  // prev tile's LDS reads done
#pragma unroll
    for (int p = 0; p < 2; ++p) {
      const int row = r8 + p * 32;
      const int u = ((row >> 4) << 7) + ((c8 >> 2) << 6) + ((c8 & 3) << 4) + ((row & 15) ^ c8);
      u16x8 v;
      v[0] = f2bf(xa[p][0].x); v[1] = f2bf(xa[p][0].y);
      v[2] = f2bf(xa[p][0].z); v[3] = f2bf(xa[p][0].w);
      v[4] = f2bf(xa[p][1].x); v[5] = f2bf(xa[p][1].y);
      v[6] = f2bf(xa[p][1].z); v[7] = f2bf(xa[p][1].w);
      *(u16x8*)(lds + u * 8) = v;
    }
#pragma unroll
    for (int p = 0; p < 2; ++p) {
      const int row = r8 + p * 32;
      const int u = 512 + ((row >> 4) << 7) + ((c8 >> 2) << 6) + ((c8 & 3) << 4) + ((row & 15) ^ c8);
      *(uint4*)(lds + u * 8) = wb[p];
    }
    __syncthreads();
#pragma unroll
    for (int ks = 0; ks < 2; ++ks) {
      const int xr = lr ^ (ks * 4 + lg);
      const bf16x8 a = *(const bf16x8*)(lds + ((w << 7) + (ks << 6) + (lg << 4) + xr) * 8);
      const bf16x8 b0 = *(const bf16x8*)(lds + (512 + (0 << 7) + (ks << 6) + (lg << 4) + xr) * 8);
      const bf16x8 b1 = *(const bf16x8*)(lds + (512 + (1 << 7) + (ks << 6) + (lg << 4) + xr) * 8);
      const bf16x8 b2 = *(const bf16x8*)(lds + (512 + (2 << 7) + (ks << 6) + (lg << 4) + xr) * 8);
      const bf16x8 b3 = *(const bf16x8*)(lds + (512 + (3 << 7) + (ks << 6) + (lg << 4) + xr) * 8);
      acc[0] = __builtin_amdgcn_mfma_f32_16x16x32_bf16(a, b0, acc[0], 0, 0, 0);
      acc[1] = __builtin_amdgcn_mfma_f32_16x16x32_bf16(a, b1, acc[1], 0, 0, 0);
      acc[2] = __builtin_amdgcn_mfma_f32_16x16x32_bf16(a, b2, acc[2], 0, 0, 0);
      acc[3] = __builtin_amdgcn_mfma_f32_16x16x32_bf16(a, b3, acc[3], 0, 0, 0);
    }
  }
  // ---- C-write; C/D layout: row=(l>>4)*4+q, col=l&15 (m89-verified) ----
#pragma unroll
  for (int cb = 0; cb < 4; ++cb)
#pragma unroll
    for (int q = 0; q < 4; ++q) {
      const int row = bm + w * 16 + lg * 4 + q;
      h1b[(size_t)row * 256 + bn + cb * 16 + lr] = f2bf(acc[cb][q]);
    }
  // ---- fused f1: partial dots over this tile's 64 cols, atomicAdd per row ----
  float a1sv[4], a1dv[4];
#pragma unroll
  for (int cb = 0; cb < 4; ++cb) {
    a1sv[cb] = A1S[bn + cb * 16 + lr];
    a1dv[cb] = A1D[bn + cb * 16 + lr];
  }
#pragma unroll
  for (int q = 0; q < 4; ++q) {
    float ps = 0.f, pd = 0.f;
#pragma unroll
    for (int cb = 0; cb < 4; ++cb) {
      ps = fmaf(acc[cb][q], a1sv[cb], ps);
      pd = fmaf(acc[cb][q], a1dv[cb], pd);
    }
#pragma unroll
    for (int off = 8; off; off >>= 1) {
      ps += __shfl_xor(ps, off, 16);
      pd += __shfl_xor(pd, off, 16);
    }
    if (lr == 0) {
      const int row = bm + w * 16 + lg * 4 + q;
      atomicAdd(f1s + row, ps);
      atomicAdd(f1d + row, pd);
    }
  }
}

// ---------- build CSR in place over the bitmap ----------
__global__ __launch_bounds__(256) void build_csr_kernel(unsigned* __restrict__ bitmap,
                                                        int* __restrict__ deg) {
  const int lane = threadIdx.x & 63;
  const int row = blockIdx.x * 4 + (threadIdx.x >> 6);
  unsigned* brow = bitmap + (size_t)row * 256;
  const uint4 wv = *(const uint4*)(brow + lane * 4);
  const int cnt = __popc(wv.x) + __popc(wv.y) + __popc(wv.z) + __popc(wv.w);
  int inc = cnt;
#pragma unroll
  for (int d = 1; d < 64; d <<= 1) {
    const int t = __shfl_up(inc, d);
    if (lane >= d) inc += t;
  }
  int off = inc - cnt;  // exclusive prefix
  const int total = __shfl(inc, 63);
  unsigned short* nb = (unsigned short*)brow;
  const unsigned words[4] = {wv.x, wv.y, wv.z, wv.w};
  const int base_j = lane * 128;
#pragma unroll
  for (int q = 0; q < 4; ++q) {
    unsigned word = words[q];
    while (word) {
      const int b = __ffs(word) - 1;
      word &= word - 1;
      nb[off++] = (unsigned short)(base_j + q * 32 + b);
    }
  }
  if (lane == 0) deg[row] = total;
}

// ---------- layer-1 attention: parallel weights; gather = 2 nbrs/wave, 16B/lane ----------
__global__ __launch_bounds__(256) void attn1_kernel(const unsigned* __restrict__ bitmap,
                                                    const int* __restrict__ degarr,
                                                    const unsigned short* __restrict__ h1b,
                                                    const float* __restrict__ fs,
                                                    const float* __restrict__ fd,
                                                    unsigned short* __restrict__ out1b) {
  __shared__ float wsh[4][MAXD];
  __shared__ int jsh[4][MAXD];
  const int lane = threadIdx.x & 63;
  const int wv = threadIdx.x >> 6;
  const int row = blockIdx.x * 4 + wv;
  const unsigned short* nb = (const unsigned short*)(bitmap + (size_t)row * 256);
  const int deg = degarr[row];
  const float fsr = fs[row];
  // ---- weight phase: lane k handles neighbors k and k+64 ----
  const int j0 = (lane < deg) ? (int)nb[lane] : 0;
  const int j1 = (lane + 64 < deg) ? (int)nb[lane + 64] : 0;
  const float e0 = (lane < deg) ? lrelu02(fsr + fd[j0]) : -1e30f;
  const float e1 = (lane + 64 < deg) ? lrelu02(fsr + fd[j1]) : -1e30f;
  float m = fmaxf(e0, e1);
#pragma unroll
  for (int off = 32; off; off >>= 1) m = fmaxf(m, __shfl_xor(m, off));
  const float w0 = (lane < deg) ? expf(e0 - m) : 0.f;
  const float w1 = (lane + 64 < deg) ? expf(e1 - m) : 0.f;
  float s = w0 + w1;
#pragma unroll
  for (int off = 32; off; off >>= 1) s += __shfl_xor(s, off);
  wsh[wv][lane] = w0;
  jsh[wv][lane] = j0;
  wsh[wv][lane + 64] = w1;
  jsh[wv][lane + 64] = j1;
  // same-wave LDS produce->consume; compiler inserts lgkmcnt
  // ---- gather: halves of the wave take alternating neighbors; 16B per lane ----
  const int half = lane >> 5, lh = lane & 31;
  float acc[8] = {0.f, 0.f, 0.f, 0.f, 0.f, 0.f, 0.f, 0.f};
  int t = 0;
  for (; t + 8 <= deg; t += 8) {  // 4 pairs -> 4 independent 16B loads in flight
    const int ja = jsh[wv][t + half], jb = jsh[wv][t + 2 + half];
    const int jc = jsh[wv][t + 4 + half], jd = jsh[wv][t + 6 + half];
    const float Wa = wsh[wv][t + half], Wb = wsh[wv][t + 2 + half];
    const float Wc = wsh[wv][t + 4 + half], Wd = wsh[wv][t + 6 + half];
    const u16x8 va = *(const u16x8*)(h1b + (size_t)ja * 256 + lh * 8);
    const u16x8 vb = *(const u16x8*)(h1b + (size_t)jb * 256 + lh * 8);
    const u16x8 vc = *(const u16x8*)(h1b + (size_t)jc * 256 + lh * 8);
    const u16x8 vd = *(const u16x8*)(h1b + (size_t)jd * 256 + lh * 8);
#pragma unroll
    for (int e = 0; e < 8; ++e)
      acc[e] = fmaf(Wa, bf2f(va[e]),
               fmaf(Wb, bf2f(vb[e]), fmaf(Wc, bf2f(vc[e]), fmaf(Wd, bf2f(vd[e]), acc[e]))));
  }
  for (; t < deg; t += 2) {  // tail pairs (odd tail: half 1 gets weight 0)
    const int idx = t + half;
    const int jt = (idx < deg) ? jsh[wv][idx] : 0;
    const float Wt = (idx < deg) ? wsh[wv][idx] : 0.f;
    const u16x8 v = *(const u16x8*)(h1b + (size_t)jt * 256 + lh * 8);
#pragma unroll
    for (int e = 0; e < 8; ++e) acc[e] = fmaf(Wt, bf2f(v[e]), acc[e]);
  }
  // combine the two halves
#pragma unroll
  for (int e = 0; e < 8; ++e) acc[e] += __shfl_xor(acc[e], 32);
  const float inv = 1.f / s;
  u16x8 o;
#pragma unroll
  for (int e = 0; e < 8; ++e) {
    float v = acc[e] * inv;
    v = v > 0.f ? v : expf(v) - 1.f;  // elu
    o[e] = f2bf(v);
  }
  if (lane < 32) *(u16x8*)(out1b + (size_t)row * 256 + lh * 8) = o;
}

// ---------- GEMM2 (MFMA) + fused f2: h2 = out1b @ W2, fs/fd = h2 . a2 ----------
__global__ __launch_bounds__(256) void gemm2f2_kernel(
    const unsigned short* __restrict__ out1b, const unsigned short* __restrict__ W2t,
    const float* __restrict__ a2s, const float* __restrict__ a2d,
    float* __restrict__ h2, float* __restrict__ fs, float* __restrict__ fd) {
  const int l = threadIdx.x & 63, w = threadIdx.x >> 6;
  const int row0 = blockIdx.x * 64 + w * 16;
  const int lr = l & 15, lg = l >> 4;
  f32x4 acc = {0.f, 0.f, 0.f, 0.f};
#pragma unroll
  for (int k0 = 0; k0 < 256; k0 += 32) {
    const bf16x8 a = *(const bf16x8*)(out1b + (size_t)(row0 + lr) * 256 + k0 + lg * 8);
    const bf16x8 b = *(const bf16x8*)(W2t + (size_t)lr * 256 + k0 + lg * 8);
    acc = __builtin_amdgcn_mfma_f32_16x16x32_bf16(a, b, acc, 0, 0, 0);
  }
  const float as = a2s[lr], ad = a2d[lr];
#pragma unroll
  for (int q = 0; q < 4; ++q) {
    const int row = row0 + lg * 4 + q;  // C/D: row=(l>>4)*4+q, col=l&15
    const float v = acc[q];
    h2[(size_t)row * 16 + lr] = v;
    float ss = v * as, dd = v * ad;
#pragma unroll
    for (int off = 8; off; off >>= 1) {
      ss += __shfl_xor(ss, off, 16);
      dd += __shfl_xor(dd, off, 16);
    }
    if (lr == 0) {
      fs[row] = ss;
      fd[row] = dd;
    }
  }
}

// ---------- layer-2 attention + final log_softmax over 16 classes ----------
__global__ __launch_bounds__(256) void attn2_kernel(const unsigned* __restrict__ bitmap,
                                                    const int* __restrict__ degarr,
                                                    const float* __restrict__ h2,
                                                    const float* __restrict__ fs,
                                                    const float* __restrict__ fd,
                                                    float* __restrict__ out) {
  __shared__ float wsh[4][MAXD];
  __shared__ int jsh[4][MAXD];
  const int lane = threadIdx.x & 63;
  const int wv = threadIdx.x >> 6;
  const int row = blockIdx.x * 4 + wv;
  const unsigned short* nb = (const unsigned short*)(bitmap + (size_t)row * 256);
  const int deg = degarr[row];
  const float fsr = fs[row];
  const int j0 = (lane < deg) ? (int)nb[lane] : 0;
  const int j1 = (lane + 64 < deg) ? (int)nb[lane + 64] : 0;
  const float e0 = (lane < deg) ? lrelu02(fsr + fd[j0]) : -1e30f;
  const float e1 = (lane + 64 < deg) ? lrelu02(fsr + fd[j1]) : -1e30f;
  float m = fmaxf(e0, e1);
#pragma unroll
  for (int off = 32; off; off >>= 1) m = fmaxf(m, __shfl_xor(m, off));
  const float w0 = (lane < deg) ? expf(e0 - m) : 0.f;
  const float w1 = (lane + 64 < deg) ? expf(e1 - m) : 0.f;
  float s = w0 + w1;
#pragma unroll
  for (int off = 32; off; off >>= 1) s += __shfl_xor(s, off);
  wsh[wv][lane] = w0;
  jsh[wv][lane] = j0;
  wsh[wv][lane + 64] = w1;
  jsh[wv][lane + 64] = j1;
  // ---- gather: 4 neighbors at a time (lane = group*16 + class), x4 in flight ----
  const int c = lane & 15, g = lane >> 4;
  float acc = 0.f;
  int t = g;
  for (; t + 12 < deg; t += 16) {
    const float W0 = wsh[wv][t], W1 = wsh[wv][t + 4];
    const float W2 = wsh[wv][t + 8], W3 = wsh[wv][t + 12];
    const float v0 = h2[(size_t)jsh[wv][t] * 16 + c];
    const float v1 = h2[(size_t)jsh[wv][t + 4] * 16 + c];
    const float v2 = h2[(size_t)jsh[wv][t + 8] * 16 + c];
    const float v3 = h2[(size_t)jsh[wv][t + 12] * 16 + c];
    acc = fmaf(W0, v0, fmaf(W1, v1, fmaf(W2, v2, fmaf(W3, v3, acc))));
  }
  for (; t < deg; t += 4) acc = fmaf(wsh[wv][t], h2[(size_t)jsh[wv][t] * 16 + c], acc);
  acc += __shfl_xor(acc, 16);
  acc += __shfl_xor(acc, 32);
  const float v = acc / s;  // logits
  float mx = v;
#pragma unroll
  for (int off = 8; off; off >>= 1) mx = fmaxf(mx, __shfl_xor(mx, off, 16));
  float se = expf(v - mx);
#pragma unroll
  for (int off = 8; off; off >>= 1) se += __shfl_xor(se, off, 16);
  if (lane < 16) out[(size_t)row * 16 + lane] = v - mx - logf(se);
}

extern "C" void kernel_launch(void* const* d_in, const int* in_sizes, int n_in,
                              void* d_out, int out_size, void* d_ws, size_t ws_size,
                              hipStream_t stream) {
  const float* x = (const float*)d_in[0];
  const int* ei = (const int*)d_in[1];
  const float* W1 = (const float*)d_in[2];
  const float* a1s = (const float*)d_in[3];
  const float* a1d = (const float*)d_in[4];
  const float* W2 = (const float*)d_in[5];
  const float* a2s = (const float*)d_in[6];
  const float* a2d = (const float*)d_in[7];
  float* out = (float*)d_out;
  const int E = in_sizes[1] / 2;
  const int SB = (E + 255) / 256;  // scatter blocks

  char* ws = (char*)d_ws;
  unsigned short* h1b = (unsigned short*)ws;           // 4 MB
  unsigned short* out1b = (unsigned short*)(ws + (4u << 20));  // 4 MB
  unsigned* bitmap = (unsigned*)(ws + (16u << 20));    // 8 MB, reused as CSR
  float* f1s = (float*)(ws + (24u << 20));
  float* f1d = f1s + NN;
  float* h2 = f1d + NN;                                // 512 KB
  float* f2s = h2 + (size_t)NN * 16;
  float* f2d = f2s + NN;
  int* deg = (int*)(f2d + NN);
  unsigned short* w1t = (unsigned short*)(deg + NN);   // 256 KB
  unsigned short* w2t = w1t + (size_t)256 * 512;       // 8 KB

  prep_kernel<<<2562, 256, 0, stream>>>((uint4*)bitmap, W1, w1t, W2, w2t, (float4*)f1s);
  gemm1_scatter_kernel<<<SB + 512, 256, 0, stream>>>(x, w1t, h1b, a1s, a1d, f1s, f1d,
                                                     ei, E, SB, bitmap);
  build_csr_kernel<<<NN / 4, 256, 0, stream>>>(bitmap, deg);
  attn1_kernel<<<NN / 4, 256, 0, stream>>>(bitmap, deg, h1b, f1s, f1d, out1b);
  gemm2f2_kernel<<<NN / 64, 256, 0, stream>>>(out1b, w2t, a2s, a2d, h2, f2s, f2d);
  attn2_kernel<<<NN / 4, 256, 0, stream>>>(bitmap, deg, h2, f2s, f2d, out);
}

// Round 15
// 67.768 us; speedup vs baseline: 13.8502x; 1.0484x over previous
//
#include <hip/hip_runtime.h>
#include <hip/hip_bf16.h>

// GAT, 2 layers, N=8192 nodes, sparse adjacency (~270K edges incl. self-loops).
// Masked softmax with -1e9 fill == sparse neighbor softmax (exp underflows to 0).
// Round 15: launch-count proven irrelevant (R14: 7->6 launches = +1.8us; fixed
// ~40us is per-replay, not per-launch). Revert scatter merge; cut real work:
// build_csr kernel DELETED — attn1 builds the CSR in-wave from the bitmap row
// (uint4/lane + popc/scan -> LDS list), uses it locally, persists ushort list
// + deg for attn2. 6 launches, one full 8MB bitmap pass removed.
// Workspace layout (~26 MB): unchanged from round 8.

#define NN 8192
#define MAXD 128  // weight-phase slots; P(in-degree>128) ~ 1e-18 (Poisson 32)

typedef __bf16 bf16x8 __attribute__((ext_vector_type(8)));
typedef float f32x4 __attribute__((ext_vector_type(4)));
typedef unsigned short u16x8 __attribute__((ext_vector_type(8)));

__device__ __forceinline__ unsigned short f2bf(float f) {
  unsigned u = __float_as_uint(f);
  unsigned r = (u + 0x7fffu + ((u >> 16) & 1u)) >> 16;  // round-nearest-even
  return (unsigned short)r;
}
__device__ __forceinline__ float bf2f(unsigned short u) {
  return __uint_as_float(((unsigned)u) << 16);
}
__device__ __forceinline__ float lrelu02(float e) { return e > 0.f ? e : 0.2f * e; }

// ---------- prep: zero bitmap + f1s/f1d, W1^T bf16, W2^T bf16 ----------
__global__ __launch_bounds__(256) void prep_kernel(uint4* __restrict__ bitmap,
                                                   const float* __restrict__ W1,
                                                   unsigned short* __restrict__ W1t,
                                                   const float* __restrict__ W2,
                                                   unsigned short* __restrict__ W2t,
                                                   float4* __restrict__ f1sd) {
  const int bid = blockIdx.x, tid = threadIdx.x;
  if (bid < 2048) {
    bitmap[bid * 256 + tid] = uint4{0u, 0u, 0u, 0u};
  } else if (bid < 2560) {
    const int gid = (bid - 2048) * 256 + tid;  // 131072 total
    const int n = gid >> 9, k = gid & 511;
    W1t[gid] = f2bf(W1[(size_t)k * 256 + n]);  // W1t[n][k]
  } else if (bid == 2560) {
    for (int i = tid; i < 16 * 256; i += 256) {
      const int n = i >> 8, k = i & 255;
      W2t[i] = f2bf(W2[(size_t)k * 16 + n]);   // W2t[n][k]
    }
  } else {
    // zero f1s[8192] ++ f1d[8192] (contiguous): 4096 float4
    for (int i = tid; i < 4096; i += 256) f1sd[i] = float4{0.f, 0.f, 0.f, 0.f};
  }
}

// ---------- scatter edges into bitmap (dedup via OR) ----------
__global__ void scatter_kernel(const int* __restrict__ ei, int E,
                               unsigned* __restrict__ bitmap) {
  const int t = blockIdx.x * 256 + threadIdx.x;
  if (t >= E) return;
  const int s = ei[t];
  const int d = ei[E + t];
  atomicOr(bitmap + (size_t)s * 256 + (d >> 5), 1u << (d & 31));
}

// ---------- GEMM1 (MFMA) + fused f1: h1b = bf16(x @ W1); f1s/f1d += partials ----------
// 64x64 tile, BK=64, 4 waves; XOR-swizzled LDS (round-10 verified: write-side
// conflict-free, read 2-way=free; A/B share map -> k-perm cancels). grid
// (128,4): bn-siblings of one bm share an XCD (dispatch idx = y*128+x, 128%8==0)
// so the X row-panel is read from L3 once and L2-hit 3x.
__global__ __launch_bounds__(256) void gemm1_mfma_kernel(
    const float* __restrict__ X, const unsigned short* __restrict__ W1t,
    unsigned short* __restrict__ h1b, const float* __restrict__ A1S,
    const float* __restrict__ A1D, float* __restrict__ f1s, float* __restrict__ f1d) {
  constexpr int K = 512;
  __shared__ __align__(16) unsigned short lds[1024 * 8];  // 512 A + 512 B units = 16 KB
  const int t = threadIdx.x;
  const int w = t >> 6, l = t & 63;
  const int lr = l & 15, lg = l >> 4;
  const int bm = blockIdx.x * 64, bn = blockIdx.y * 64;
  const int r8 = t >> 3, c8 = t & 7;  // staging coords: row r8(+32), 16B k-chunk c8

  f32x4 acc[4];
  const f32x4 fz = {0.f, 0.f, 0.f, 0.f};
#pragma unroll
  for (int cb = 0; cb < 4; ++cb) acc[cb] = fz;

  for (int k0 = 0; k0 < K; k0 += 64) {
    float4 xa[2][2];
#pragma unroll
    for (int p = 0; p < 2; ++p) {
      const float* s = X + (size_t)(bm + r8 + p * 32) * K + k0 + c8 * 8;
      xa[p][0] = *(const float4*)s;
      xa[p][1] = *(const float4*)(s + 4);
    }
    uint4 wb[2];
#pragma unroll
    for (int p = 0; p < 2; ++p)
      wb[p] = *(const uint4*)(W1t + (size_t)(bn + r8 + p * 32) * K + k0 + c8 * 8);
    __syncthreads();  // prev tile's LDS reads done
#pragma unroll
    for (int p = 0; p < 2; ++p) {
      const int row = r8 + p * 32;
      const int u = ((row >> 4) << 7) + ((c8 >> 2) << 6) + ((c8 & 3) << 4) + ((row & 15) ^ c8);
      u16x8 v;
      v[0] = f2bf(xa[p][0].x); v[1] = f2bf(xa[p][0].y);
      v[2] = f2bf(xa[p][0].z); v[3] = f2bf(xa[p][0].w);
      v[4] = f2bf(xa[p][1].x); v[5] = f2bf(xa[p][1].y);
      v[6] = f2bf(xa[p][1].z); v[7] = f2bf(xa[p][1].w);
      *(u16x8*)(lds + u * 8) = v;
    }
#pragma unroll
    for (int p = 0; p < 2; ++p) {
      const int row = r8 + p * 32;
      const int u = 512 + ((row >> 4) << 7) + ((c8 >> 2) << 6) + ((c8 & 3) << 4) + ((row & 15) ^ c8);
      *(uint4*)(lds + u * 8) = wb[p];
    }
    __syncthreads();
#pragma unroll
    for (int ks = 0; ks < 2; ++ks) {
      const int xr = lr ^ (ks * 4 + lg);
      const bf16x8 a = *(const bf16x8*)(lds + ((w << 7) + (ks << 6) + (lg << 4) + xr) * 8);
      const bf16x8 b0 = *(const bf16x8*)(lds + (512 + (0 << 7) + (ks << 6) + (lg << 4) + xr) * 8);
      const bf16x8 b1 = *(const bf16x8*)(lds + (512 + (1 << 7) + (ks << 6) + (lg << 4) + xr) * 8);
      const bf16x8 b2 = *(const bf16x8*)(lds + (512 + (2 << 7) + (ks << 6) + (lg << 4) + xr) * 8);
      const bf16x8 b3 = *(const bf16x8*)(lds + (512 + (3 << 7) + (ks << 6) + (lg << 4) + xr) * 8);
      acc[0] = __builtin_amdgcn_mfma_f32_16x16x32_bf16(a, b0, acc[0], 0, 0, 0);
      acc[1] = __builtin_amdgcn_mfma_f32_16x16x32_bf16(a, b1, acc[1], 0, 0, 0);
      acc[2] = __builtin_amdgcn_mfma_f32_16x16x32_bf16(a, b2, acc[2], 0, 0, 0);
      acc[3] = __builtin_amdgcn_mfma_f32_16x16x32_bf16(a, b3, acc[3], 0, 0, 0);
    }
  }
  // ---- C-write; C/D layout: row=(l>>4)*4+q, col=l&15 (m89-verified) ----
#pragma unroll
  for (int cb = 0; cb < 4; ++cb)
#pragma unroll
    for (int q = 0; q < 4; ++q) {
      const int row = bm + w * 16 + lg * 4 + q;
      h1b[(size_t)row * 256 + bn + cb * 16 + lr] = f2bf(acc[cb][q]);
    }
  // ---- fused f1: partial dots over this tile's 64 cols, atomicAdd per row ----
  float a1sv[4], a1dv[4];
#pragma unroll
  for (int cb = 0; cb < 4; ++cb) {
    a1sv[cb] = A1S[bn + cb * 16 + lr];
    a1dv[cb] = A1D[bn + cb * 16 + lr];
  }
#pragma unroll
  for (int q = 0; q < 4; ++q) {
    float ps = 0.f, pd = 0.f;
#pragma unroll
    for (int cb = 0; cb < 4; ++cb) {
      ps = fmaf(acc[cb][q], a1sv[cb], ps);
      pd = fmaf(acc[cb][q], a1dv[cb], pd);
    }
#pragma unroll
    for (int off = 8; off; off >>= 1) {
      ps += __shfl_xor(ps, off, 16);
      pd += __shfl_xor(pd, off, 16);
    }
    if (lr == 0) {
      const int row = bm + w * 16 + lg * 4 + q;
      atomicAdd(f1s + row, ps);
      atomicAdd(f1d + row, pd);
    }
  }
}

// ---------- layer-1 attention + in-wave CSR build ----------
// Per wave: read own bitmap row (uint4/lane = 1KB), popc + shuffle prefix-scan,
// extract neighbor indices into LDS (used locally by the weight phase), persist
// ushort list + deg to global (in-place over the consumed bitmap row) for attn2.
__global__ __launch_bounds__(256) void attn1_kernel(unsigned* __restrict__ bitmap,
                                                    int* __restrict__ degarr,
                                                    const unsigned short* __restrict__ h1b,
                                                    const float* __restrict__ fs,
                                                    const float* __restrict__ fd,
                                                    unsigned short* __restrict__ out1b) {
  __shared__ float wsh[4][MAXD];
  __shared__ int jsh[4][MAXD];
  const int lane = threadIdx.x & 63;
  const int wv = threadIdx.x >> 6;
  const int row = blockIdx.x * 4 + wv;
  unsigned* brow = bitmap + (size_t)row * 256;
  // ---- in-wave CSR build (replaces build_csr_kernel) ----
  const uint4 wq = *(const uint4*)(brow + lane * 4);
  const int cnt = __popc(wq.x) + __popc(wq.y) + __popc(wq.z) + __popc(wq.w);
  int inc = cnt;
#pragma unroll
  for (int d = 1; d < 64; d <<= 1) {
    const int t2 = __shfl_up(inc, d);
    if (lane >= d) inc += t2;
  }
  int off = inc - cnt;  // exclusive prefix
  const int deg = __shfl(inc, 63);
  {
    const unsigned words[4] = {wq.x, wq.y, wq.z, wq.w};
    const int base_j = lane * 128;
#pragma unroll
    for (int q = 0; q < 4; ++q) {
      unsigned word = words[q];
      while (word) {
        const int b = __ffs(word) - 1;
        word &= word - 1;
        jsh[wv][off++] = base_j + q * 32 + b;
      }
    }
  }
  if (lane == 0) degarr[row] = deg;
  // persist ushort list for attn2 (in-place; row already consumed into regs)
  {
    unsigned short* nbp = (unsigned short*)brow;
    if (lane < deg) nbp[lane] = (unsigned short)jsh[wv][lane];
    if (lane + 64 < deg) nbp[lane + 64] = (unsigned short)jsh[wv][lane + 64];
  }
  const float fsr = fs[row];
  // ---- weight phase: lane k handles neighbors k and k+64 (from LDS) ----
  const int j0 = (lane < deg) ? jsh[wv][lane] : 0;
  const int j1 = (lane + 64 < deg) ? jsh[wv][lane + 64] : 0;
  const float e0 = (lane < deg) ? lrelu02(fsr + fd[j0]) : -1e30f;
  const float e1 = (lane + 64 < deg) ? lrelu02(fsr + fd[j1]) : -1e30f;
  float m = fmaxf(e0, e1);
#pragma unroll
  for (int off2 = 32; off2; off2 >>= 1) m = fmaxf(m, __shfl_xor(m, off2));
  const float w0 = (lane < deg) ? expf(e0 - m) : 0.f;
  const float w1 = (lane + 64 < deg) ? expf(e1 - m) : 0.f;
  float s = w0 + w1;
#pragma unroll
  for (int off2 = 32; off2; off2 >>= 1) s += __shfl_xor(s, off2);
  wsh[wv][lane] = w0;
  wsh[wv][lane + 64] = w1;
  // same-wave LDS produce->consume; compiler inserts lgkmcnt
  // ---- gather: halves of the wave take alternating neighbors; 16B per lane ----
  const int half = lane >> 5, lh = lane & 31;
  float acc[8] = {0.f, 0.f, 0.f, 0.f, 0.f, 0.f, 0.f, 0.f};
  int t = 0;
  for (; t + 8 <= deg; t += 8) {  // 4 pairs -> 4 independent 16B loads in flight
    const int ja = jsh[wv][t + half], jb = jsh[wv][t + 2 + half];
    const int jc = jsh[wv][t + 4 + half], jd = jsh[wv][t + 6 + half];
    const float Wa = wsh[wv][t + half], Wb = wsh[wv][t + 2 + half];
    const float Wc = wsh[wv][t + 4 + half], Wd = wsh[wv][t + 6 + half];
    const u16x8 va = *(const u16x8*)(h1b + (size_t)ja * 256 + lh * 8);
    const u16x8 vb = *(const u16x8*)(h1b + (size_t)jb * 256 + lh * 8);
    const u16x8 vc = *(const u16x8*)(h1b + (size_t)jc * 256 + lh * 8);
    const u16x8 vd = *(const u16x8*)(h1b + (size_t)jd * 256 + lh * 8);
#pragma unroll
    for (int e = 0; e < 8; ++e)
      acc[e] = fmaf(Wa, bf2f(va[e]),
               fmaf(Wb, bf2f(vb[e]), fmaf(Wc, bf2f(vc[e]), fmaf(Wd, bf2f(vd[e]), acc[e]))));
  }
  for (; t < deg; t += 2) {  // tail pairs (odd tail: half 1 gets weight 0)
    const int idx = t + half;
    const int jt = (idx < deg) ? jsh[wv][idx] : 0;
    const float Wt = (idx < deg) ? wsh[wv][idx] : 0.f;
    const u16x8 v = *(const u16x8*)(h1b + (size_t)jt * 256 + lh * 8);
#pragma unroll
    for (int e = 0; e < 8; ++e) acc[e] = fmaf(Wt, bf2f(v[e]), acc[e]);
  }
  // combine the two halves
#pragma unroll
  for (int e = 0; e < 8; ++e) acc[e] += __shfl_xor(acc[e], 32);
  const float inv = 1.f / s;
  u16x8 o;
#pragma unroll
  for (int e = 0; e < 8; ++e) {
    float v = acc[e] * inv;
    v = v > 0.f ? v : expf(v) - 1.f;  // elu
    o[e] = f2bf(v);
  }
  if (lane < 32) *(u16x8*)(out1b + (size_t)row * 256 + lh * 8) = o;
}

// ---------- GEMM2 (MFMA) + fused f2: h2 = out1b @ W2, fs/fd = h2 . a2 ----------
__global__ __launch_bounds__(256) void gemm2f2_kernel(
    const unsigned short* __restrict__ out1b, const unsigned short* __restrict__ W2t,
    const float* __restrict__ a2s, const float* __restrict__ a2d,
    float* __restrict__ h2, float* __restrict__ fs, float* __restrict__ fd) {
  const int l = threadIdx.x & 63, w = threadIdx.x >> 6;
  const int row0 = blockIdx.x * 64 + w * 16;
  const int lr = l & 15, lg = l >> 4;
  f32x4 acc = {0.f, 0.f, 0.f, 0.f};
#pragma unroll
  for (int k0 = 0; k0 < 256; k0 += 32) {
    const bf16x8 a = *(const bf16x8*)(out1b + (size_t)(row0 + lr) * 256 + k0 + lg * 8);
    const bf16x8 b = *(const bf16x8*)(W2t + (size_t)lr * 256 + k0 + lg * 8);
    acc = __builtin_amdgcn_mfma_f32_16x16x32_bf16(a, b, acc, 0, 0, 0);
  }
  const float as = a2s[lr], ad = a2d[lr];
#pragma unroll
  for (int q = 0; q < 4; ++q) {
    const int row = row0 + lg * 4 + q;  // C/D: row=(l>>4)*4+q, col=l&15
    const float v = acc[q];
    h2[(size_t)row * 16 + lr] = v;
    float ss = v * as, dd = v * ad;
#pragma unroll
    for (int off = 8; off; off >>= 1) {
      ss += __shfl_xor(ss, off, 16);
      dd += __shfl_xor(dd, off, 16);
    }
    if (lr == 0) {
      fs[row] = ss;
      fd[row] = dd;
    }
  }
}

// ---------- layer-2 attention + final log_softmax over 16 classes ----------
__global__ __launch_bounds__(256) void attn2_kernel(const unsigned* __restrict__ bitmap,
                                                    const int* __restrict__ degarr,
                                                    const float* __restrict__ h2,
                                                    const float* __restrict__ fs,
                                                    const float* __restrict__ fd,
                                                    float* __restrict__ out) {
  __shared__ float wsh[4][MAXD];
  __shared__ int jsh[4][MAXD];
  const int lane = threadIdx.x & 63;
  const int wv = threadIdx.x >> 6;
  const int row = blockIdx.x * 4 + wv;
  const unsigned short* nb = (const unsigned short*)(bitmap + (size_t)row * 256);
  const int deg = degarr[row];
  const float fsr = fs[row];
  const int j0 = (lane < deg) ? (int)nb[lane] : 0;
  const int j1 = (lane + 64 < deg) ? (int)nb[lane + 64] : 0;
  const float e0 = (lane < deg) ? lrelu02(fsr + fd[j0]) : -1e30f;
  const float e1 = (lane + 64 < deg) ? lrelu02(fsr + fd[j1]) : -1e30f;
  float m = fmaxf(e0, e1);
#pragma unroll
  for (int off = 32; off; off >>= 1) m = fmaxf(m, __shfl_xor(m, off));
  const float w0 = (lane < deg) ? expf(e0 - m) : 0.f;
  const float w1 = (lane + 64 < deg) ? expf(e1 - m) : 0.f;
  float s = w0 + w1;
#pragma unroll
  for (int off = 32; off; off >>= 1) s += __shfl_xor(s, off);
  wsh[wv][lane] = w0;
  jsh[wv][lane] = j0;
  wsh[wv][lane + 64] = w1;
  jsh[wv][lane + 64] = j1;
  // ---- gather: 4 neighbors at a time (lane = group*16 + class), x4 in flight ----
  const int c = lane & 15, g = lane >> 4;
  float acc = 0.f;
  int t = g;
  for (; t + 12 < deg; t += 16) {
    const float W0 = wsh[wv][t], W1 = wsh[wv][t + 4];
    const float W2 = wsh[wv][t + 8], W3 = wsh[wv][t + 12];
    const float v0 = h2[(size_t)jsh[wv][t] * 16 + c];
    const float v1 = h2[(size_t)jsh[wv][t + 4] * 16 + c];
    const float v2 = h2[(size_t)jsh[wv][t + 8] * 16 + c];
    const float v3 = h2[(size_t)jsh[wv][t + 12] * 16 + c];
    acc = fmaf(W0, v0, fmaf(W1, v1, fmaf(W2, v2, fmaf(W3, v3, acc))));
  }
  for (; t < deg; t += 4) acc = fmaf(wsh[wv][t], h2[(size_t)jsh[wv][t] * 16 + c], acc);
  acc += __shfl_xor(acc, 16);
  acc += __shfl_xor(acc, 32);
  const float v = acc / s;  // logits
  float mx = v;
#pragma unroll
  for (int off = 8; off; off >>= 1) mx = fmaxf(mx, __shfl_xor(mx, off, 16));
  float se = expf(v - mx);
#pragma unroll
  for (int off = 8; off; off >>= 1) se += __shfl_xor(se, off, 16);
  if (lane < 16) out[(size_t)row * 16 + lane] = v - mx - logf(se);
}

extern "C" void kernel_launch(void* const* d_in, const int* in_sizes, int n_in,
                              void* d_out, int out_size, void* d_ws, size_t ws_size,
                              hipStream_t stream) {
  const float* x = (const float*)d_in[0];
  const int* ei = (const int*)d_in[1];
  const float* W1 = (const float*)d_in[2];
  const float* a1s = (const float*)d_in[3];
  const float* a1d = (const float*)d_in[4];
  const float* W2 = (const float*)d_in[5];
  const float* a2s = (const float*)d_in[6];
  const float* a2d = (const float*)d_in[7];
  float* out = (float*)d_out;
  const int E = in_sizes[1] / 2;

  char* ws = (char*)d_ws;
  unsigned short* h1b = (unsigned short*)ws;           // 4 MB
  unsigned short* out1b = (unsigned short*)(ws + (4u << 20));  // 4 MB
  unsigned* bitmap = (unsigned*)(ws + (16u << 20));    // 8 MB, reused as CSR
  float* f1s = (float*)(ws + (24u << 20));
  float* f1d = f1s + NN;
  float* h2 = f1d + NN;                                // 512 KB
  float* f2s = h2 + (size_t)NN * 16;
  float* f2d = f2s + NN;
  int* deg = (int*)(f2d + NN);
  unsigned short* w1t = (unsigned short*)(deg + NN);   // 256 KB
  unsigned short* w2t = w1t + (size_t)256 * 512;       // 8 KB

  prep_kernel<<<2562, 256, 0, stream>>>((uint4*)bitmap, W1, w1t, W2, w2t, (float4*)f1s);
  scatter_kernel<<<(E + 255) / 256, 256, 0, stream>>>(ei, E, bitmap);
  gemm1_mfma_kernel<<<dim3(NN / 64, 256 / 64), 256, 0, stream>>>(x, w1t, h1b, a1s, a1d,
                                                                 f1s, f1d);
  attn1_kernel<<<NN / 4, 256, 0, stream>>>(bitmap, deg, h1b, f1s, f1d, out1b);
  gemm2f2_kernel<<<NN / 64, 256, 0, stream>>>(out1b, w2t, a2s, a2d, h2, f2s, f2d);
  attn2_kernel<<<NN / 4, 256, 0, stream>>>(bitmap, deg, h2, f2s, f2d, out);
}